// Round 3
// baseline (48.095 us; speedup 1.0000x reference)
//
#include <hip/hip_runtime.h>

typedef _Float16 f16x8 __attribute__((ext_vector_type(8)));
typedef float    f32x4 __attribute__((ext_vector_type(4)));

#define BATCH 65536
#define NIN   128
#define NOUT  128

#define AS  4.2039284307525743f   /* 3.5 * sqrt(log2(e)); 1/width = (G-1)/2 = 3.5 */
#define L2E 1.4426950408889634f

// ---------------------------------------------------------------------------
// W2 layout (fp16, by kan_prep): 36 tiles of 8 KB (one per k-step).
// Tile ks, chunk c = nb*64 + lane (16 B per chunk, lane = lhi*16 + l15):
//   n = nb*16 + l15, e = 0..7:
//     ks < 32  -> coeffs[n][j = lhi*32 + ks][g = e]            (basis)
//     ks >= 32 -> base_w[n][j = lhi*32 + (ks-32)*8 + e]        (silu)
// MFMA k_local = lhi*8 + e. ds_read: 64 lanes read 1024 CONSECUTIVE bytes
// (lane*16) -> 2-way bank aliasing only (free). Groups of 4 tiles (32 KB)
// are staged with linear global_load_lds and double-buffered.
// ---------------------------------------------------------------------------

__global__ __launch_bounds__(256) void kan_prep(const float* __restrict__ coeffs,
                                                const float* __restrict__ base_w,
                                                _Float16* __restrict__ W2) {
    int t = blockIdx.x * 256 + threadIdx.x;   // chunk id, 0..18431
    int ks   = t >> 9;
    int c    = t & 511;
    int nb   = c >> 6;
    int lane = c & 63;
    int lhi  = lane >> 4;
    int l15  = lane & 15;
    int n    = nb * 16 + l15;
    const float* src;
    if (ks < 32) src = coeffs + ((size_t)n * 128 + lhi * 32 + ks) * 8;
    else         src = base_w + (size_t)n * 128 + lhi * 32 + (ks - 32) * 8;
    f16x8 v;
#pragma unroll
    for (int e = 0; e < 8; ++e) v[e] = (_Float16)src[e];
    *(f16x8*)((char*)W2 + (size_t)t * 16) = v;
}

__device__ __forceinline__ void gll16(const void* g, void* l) {
    __builtin_amdgcn_global_load_lds(
        (const __attribute__((address_space(1))) unsigned int*)g,
        (__attribute__((address_space(3))) unsigned int*)l, 16, 0, 0);
}

__device__ __forceinline__ f16x8 basis8(float xv, const float* bq) {
    f16x8 r;
#pragma unroll
    for (int g = 0; g < 8; ++g) {
        float u = __builtin_fmaf(xv, AS, bq[g]);      // sqrt(log2e)*(x-c_g)/w
        float e = __builtin_amdgcn_exp2f(-(u * u));   // exp(-((x-c)/w)^2)
        r[g] = (_Float16)e;
    }
    return r;
}

__device__ __forceinline__ float silu1(float xv) {
    float p = __builtin_amdgcn_exp2f(-xv * L2E);
    return xv * __builtin_amdgcn_rcpf(1.0f + p);
}

// 128 threads = 2 waves; wave owns 64 rows x 128 cols (4 m-frags x 8 n-frags).
// Grid 512 -> 2 blocks/CU, 4 waves/CU (1/SIMD): B ds_read amortized over 4 MFMAs.
__global__ __launch_bounds__(128) void kan_main(const float* __restrict__ x,
                                                const float* __restrict__ centers,
                                                const _Float16* __restrict__ W2,
                                                float* __restrict__ out) {
    __shared__ _Float16 smem[2][16384];   // 2 x 32 KB (4 k-step tiles each)

    const int tid  = threadIdx.x;
    const int lane = tid & 63;
    const int w    = tid >> 6;
    const int l15  = lane & 15;
    const int lhi  = lane >> 4;
    const int row0 = blockIdx.x * 128 + w * 64;

    float bq[8];
#pragma unroll
    for (int g = 0; g < 8; ++g) bq[g] = -centers[g] * AS;

    // per-lane x base: row (row0 + m*16 + l15), col stripe lhi*32 + ...
    const float* xp = x + (size_t)(row0 + l15) * NIN + lhi * 32;

    f32x4 acc[4][8];
#pragma unroll
    for (int m = 0; m < 4; ++m)
#pragma unroll
        for (int nb = 0; nb < 8; ++nb) acc[m][nb] = (f32x4){0.f, 0.f, 0.f, 0.f};

    const char* w2base = (const char*)W2;
    // stage 32 KB group: 128 threads x 16 chunks of 16 B, fully linear
#define STAGE(buf, grp)                                                         \
    do {                                                                        \
        const char* _s = w2base + (size_t)(grp) * 32768 + (size_t)tid * 16;     \
        char*       _d = (char*)&smem[(buf)][0] + (size_t)tid * 16;             \
        _Pragma("unroll")                                                       \
        for (int _i = 0; _i < 16; ++_i) gll16(_s + _i * 2048, _d + _i * 2048);  \
    } while (0)

    STAGE(0, 0);
    f32x4 xq[4];
#pragma unroll
    for (int m = 0; m < 4; ++m) xq[m] = *(const f32x4*)(xp + m * 2048);
    __syncthreads();

    // ---- 8 basis groups of 4 k-steps (K = 1024) ----
#pragma unroll 2
    for (int g = 0; g < 8; ++g) {
        const int cur = g & 1;
        STAGE(cur ^ 1, g + 1);            // next group (g=7 stages silu group)
        f32x4 xn[4];
        if (g < 7) {
#pragma unroll
            for (int m = 0; m < 4; ++m) xn[m] = *(const f32x4*)(xp + m * 2048 + (g + 1) * 4);
        }
#pragma unroll
        for (int t2 = 0; t2 < 4; ++t2) {  // k-step ks = g*4 + t2, j = lhi*32 + ks
            f16x8 a[4];
#pragma unroll
            for (int m = 0; m < 4; ++m) a[m] = basis8(xq[m][t2], bq);
            const _Float16* bp = &smem[cur][t2 * 4096 + lane * 8];
#pragma unroll
            for (int nb = 0; nb < 8; ++nb) {
                f16x8 b = *(const f16x8*)(bp + nb * 512);
#pragma unroll
                for (int m = 0; m < 4; ++m)
                    acc[m][nb] = __builtin_amdgcn_mfma_f32_16x16x32_f16(a[m], b, acc[m][nb], 0, 0, 0);
            }
        }
        if (g < 7) {
#pragma unroll
            for (int m = 0; m < 4; ++m) xq[m] = xn[m];
        }
        __syncthreads();
    }

    // ---- silu group: 4 k-steps (K = 128), tiles in buffer 0 ----
#pragma unroll
    for (int t2 = 0; t2 < 4; ++t2) {      // j = lhi*32 + t2*8 + e
        f16x8 a[4];
#pragma unroll
        for (int m = 0; m < 4; ++m) {
            f32x4 v0 = *(const f32x4*)(xp + m * 2048 + t2 * 8);
            f32x4 v1 = *(const f32x4*)(xp + m * 2048 + t2 * 8 + 4);
#pragma unroll
            for (int e = 0; e < 4; ++e) { a[m][e] = (_Float16)silu1(v0[e]); a[m][4 + e] = (_Float16)silu1(v1[e]); }
        }
        const _Float16* bp = &smem[0][t2 * 4096 + lane * 8];
#pragma unroll
        for (int nb = 0; nb < 8; ++nb) {
            f16x8 b = *(const f16x8*)(bp + nb * 512);
#pragma unroll
            for (int m = 0; m < 4; ++m)
                acc[m][nb] = __builtin_amdgcn_mfma_f32_16x16x32_f16(a[m], b, acc[m][nb], 0, 0, 0);
        }
    }

    // ---- Epilogue: D row = m*16 + lhi*4 + r, col = nb*16 + l15 ----
#pragma unroll
    for (int m = 0; m < 4; ++m)
#pragma unroll
        for (int nb = 0; nb < 8; ++nb)
#pragma unroll
            for (int r = 0; r < 4; ++r)
                out[(size_t)(row0 + m * 16 + lhi * 4 + r) * NOUT + nb * 16 + l15] = acc[m][nb][r];
}

extern "C" void kernel_launch(void* const* d_in, const int* in_sizes, int n_in,
                              void* d_out, int out_size, void* d_ws, size_t ws_size,
                              hipStream_t stream) {
    const float* x       = (const float*)d_in[0];
    const float* coeffs  = (const float*)d_in[1];
    const float* base_w  = (const float*)d_in[2];
    const float* centers = (const float*)d_in[3];
    _Float16* W2 = (_Float16*)d_ws;   // 36 * 8192 = 294912 bytes

    kan_prep<<<dim3(72), dim3(256), 0, stream>>>(coeffs, base_w, W2);
    kan_main<<<dim3(BATCH / 128), dim3(128), 0, stream>>>(x, centers, W2, (float*)d_out);
}

// Round 4
// 40.073 us; speedup vs baseline: 1.2002x; 1.2002x over previous
//
#include <hip/hip_runtime.h>

typedef _Float16 f16x8 __attribute__((ext_vector_type(8)));
typedef float    f32x4 __attribute__((ext_vector_type(4)));

#define BATCH 65536
#define NIN   128
#define NOUT  128

#define AS  4.2039284307525743f   /* 3.5 * sqrt(log2(e)); 1/width = (G-1)/2 = 3.5 */
#define L2E 1.4426950408889634f

// ---------------------------------------------------------------------------
// W2 layout (fp16, by kan_prep): 36 tiles of 8 KB (one per k-step).
// Tile ks, chunk c = nb*64 + lane (16 B per chunk, lane = lhi*16 + l15):
//   n = nb*16 + l15, e = 0..7:
//     ks < 32  -> coeffs[n][j = lhi*32 + ks][g = e]            (basis)
//     ks >= 32 -> base_w[n][j = lhi*32 + (ks-32)*8 + e]        (silu)
// MFMA k_local = lhi*8 + e. ds_read per nb-fragment: 64 lanes read 1024
// CONSECUTIVE bytes -> 2-way bank aliasing only (free; verified 0 conflicts).
// Groups of 4 tiles (32 KB) staged linearly via global_load_lds, dbuffered.
// ---------------------------------------------------------------------------

__global__ __launch_bounds__(256) void kan_prep(const float* __restrict__ coeffs,
                                                const float* __restrict__ base_w,
                                                _Float16* __restrict__ W2) {
    int t = blockIdx.x * 256 + threadIdx.x;   // chunk id, 0..18431
    int ks   = t >> 9;
    int c    = t & 511;
    int nb   = c >> 6;
    int lane = c & 63;
    int lhi  = lane >> 4;
    int l15  = lane & 15;
    int n    = nb * 16 + l15;
    const float* src;
    if (ks < 32) src = coeffs + ((size_t)n * 128 + lhi * 32 + ks) * 8;
    else         src = base_w + (size_t)n * 128 + lhi * 32 + (ks - 32) * 8;
    f16x8 v;
#pragma unroll
    for (int e = 0; e < 8; ++e) v[e] = (_Float16)src[e];
    *(f16x8*)((char*)W2 + (size_t)t * 16) = v;
}

__device__ __forceinline__ void gll16(const void* g, void* l) {
    __builtin_amdgcn_global_load_lds(
        (const __attribute__((address_space(1))) unsigned int*)g,
        (__attribute__((address_space(3))) unsigned int*)l, 16, 0, 0);
}

__device__ __forceinline__ f16x8 basis8(float xv, const float* bq) {
    f16x8 r;
#pragma unroll
    for (int g = 0; g < 8; ++g) {
        float u = __builtin_fmaf(xv, AS, bq[g]);      // sqrt(log2e)*(x-c_g)/w
        float e = __builtin_amdgcn_exp2f(-(u * u));   // exp(-((x-c)/w)^2)
        r[g] = (_Float16)e;
    }
    return r;
}

__device__ __forceinline__ float silu1(float xv) {
    float p = __builtin_amdgcn_exp2f(-xv * L2E);
    return xv * __builtin_amdgcn_rcpf(1.0f + p);
}

// 256 threads = 4 waves; wave owns 32 rows x 128 cols (m=2 x nb=8).
// Grid 512 -> 2 blocks/CU -> 8 waves/CU (2/SIMD); barriers of the two blocks
// interleave. x stripe lives entirely in registers (16 x f32x4 per lane).
__global__ __launch_bounds__(256, 2) void kan_main(const float* __restrict__ x,
                                                   const float* __restrict__ centers,
                                                   const _Float16* __restrict__ W2,
                                                   float* __restrict__ out) {
    __shared__ _Float16 smem[2][16384];   // 2 x 32 KB (4 k-step tiles each)

    const int tid  = threadIdx.x;
    const int lane = tid & 63;
    const int w    = tid >> 6;
    const int l15  = lane & 15;
    const int lhi  = lane >> 4;
    const int row0 = blockIdx.x * 128 + w * 32;

    float bq[8];
#pragma unroll
    for (int g = 0; g < 8; ++g) bq[g] = -centers[g] * AS;

    // whole x stripe in registers: rows row0+l15, row0+16+l15; cols lhi*32..+31
    const float* xp = x + (size_t)(row0 + l15) * NIN + lhi * 32;
    f32x4 xr[2][8];
#pragma unroll
    for (int m = 0; m < 2; ++m)
#pragma unroll
        for (int q = 0; q < 8; ++q) xr[m][q] = *(const f32x4*)(xp + m * 2048 + q * 4);

    f32x4 acc[2][8];
#pragma unroll
    for (int m = 0; m < 2; ++m)
#pragma unroll
        for (int nb = 0; nb < 8; ++nb) acc[m][nb] = (f32x4){0.f, 0.f, 0.f, 0.f};

    const char* w2base = (const char*)W2;
    // stage one 32 KB group (4 k-step tiles): 256 threads x 8 chunks, linear
#define STAGE(buf, grp)                                                         \
    do {                                                                        \
        const char* _s = w2base + (size_t)(grp) * 32768 + (size_t)tid * 16;     \
        char*       _d = (char*)&smem[(buf)][0] + (size_t)tid * 16;             \
        _Pragma("unroll")                                                       \
        for (int _i = 0; _i < 8; ++_i) gll16(_s + _i * 4096, _d + _i * 4096);   \
    } while (0)

    STAGE(0, 0);
    __syncthreads();

    // ---- 8 basis groups of 4 k-steps (K = 1024) ----
#pragma unroll
    for (int g = 0; g < 8; ++g) {
        const int cur = g & 1;
        STAGE(cur ^ 1, g + 1);            // g == 7 stages the silu group
#pragma unroll
        for (int t2 = 0; t2 < 4; ++t2) {  // kstep ks = g*4+t2; j = lhi*32 + ks
            f16x8 a0 = basis8(xr[0][g][t2], bq);
            f16x8 a1 = basis8(xr[1][g][t2], bq);
            const _Float16* bp = &smem[cur][t2 * 4096 + lane * 8];
#pragma unroll
            for (int nb = 0; nb < 8; ++nb) {
                f16x8 b = *(const f16x8*)(bp + nb * 512);
                acc[0][nb] = __builtin_amdgcn_mfma_f32_16x16x32_f16(a0, b, acc[0][nb], 0, 0, 0);
                acc[1][nb] = __builtin_amdgcn_mfma_f32_16x16x32_f16(a1, b, acc[1][nb], 0, 0, 0);
            }
        }
        __syncthreads();
    }

    // ---- silu group (4 k-steps, K = 128), tiles in buffer 0 ----
#pragma unroll
    for (int t2 = 0; t2 < 4; ++t2) {      // j = lhi*32 + t2*8 + e
        f16x8 a[2];
#pragma unroll
        for (int m = 0; m < 2; ++m)
#pragma unroll
            for (int e = 0; e < 4; ++e) {
                a[m][e]     = (_Float16)silu1(xr[m][t2 * 2][e]);
                a[m][4 + e] = (_Float16)silu1(xr[m][t2 * 2 + 1][e]);
            }
        const _Float16* bp = &smem[0][t2 * 4096 + lane * 8];
#pragma unroll
        for (int nb = 0; nb < 8; ++nb) {
            f16x8 b = *(const f16x8*)(bp + nb * 512);
            acc[0][nb] = __builtin_amdgcn_mfma_f32_16x16x32_f16(a[0], b, acc[0][nb], 0, 0, 0);
            acc[1][nb] = __builtin_amdgcn_mfma_f32_16x16x32_f16(a[1], b, acc[1][nb], 0, 0, 0);
        }
    }

    // ---- Epilogue: D row = m*16 + lhi*4 + r, col = nb*16 + l15 ----
#pragma unroll
    for (int m = 0; m < 2; ++m)
#pragma unroll
        for (int nb = 0; nb < 8; ++nb)
#pragma unroll
            for (int r = 0; r < 4; ++r)
                out[(size_t)(row0 + m * 16 + lhi * 4 + r) * NOUT + nb * 16 + l15] = acc[m][nb][r];
}

extern "C" void kernel_launch(void* const* d_in, const int* in_sizes, int n_in,
                              void* d_out, int out_size, void* d_ws, size_t ws_size,
                              hipStream_t stream) {
    const float* x       = (const float*)d_in[0];
    const float* coeffs  = (const float*)d_in[1];
    const float* base_w  = (const float*)d_in[2];
    const float* centers = (const float*)d_in[3];
    _Float16* W2 = (_Float16*)d_ws;   // 36 * 8192 = 294912 bytes

    kan_prep<<<dim3(72), dim3(256), 0, stream>>>(coeffs, base_w, W2);
    kan_main<<<dim3(BATCH / 128), dim3(256), 0, stream>>>(x, centers, W2, (float*)d_out);
}